// Round 13
// baseline (190.892 us; speedup 1.0000x reference)
//
#include <hip/hip_runtime.h>

typedef float f32x4 __attribute__((ext_vector_type(4)));
typedef short bf16x8 __attribute__((ext_vector_type(8)));

#define NB 8
#define NH 16
#define NSEQ 1024
#define NP 64
#define NKV 1088
#define NC 1024
#define NHD 64
#define BHSZ 69632  // per-(b,h) K/V fragment-packed size = 1088*64

__device__ __forceinline__ unsigned short f2bf(float f) {
  unsigned int u = __builtin_bit_cast(unsigned int, f);
  u += 0x7fffu + ((u >> 16) & 1u);  // RNE
  return (unsigned short)(u >> 16);
}

__device__ __forceinline__ f32x4 mfma16(bf16x8 a, bf16x8 b, f32x4 c) {
  return __builtin_amdgcn_mfma_f32_16x16x32_bf16(a, b, c, 0, 0, 0);
}

// fragment-packed address (element granularity) for a row-major [R][1024] matrix
// (GEMM A/B operands). row = panel*128 + half*64 + m*16 + lr ; k = t*64 + kk*32 + lg*8 + e
__device__ __forceinline__ size_t fa_elem(int r, int k) {
  return (size_t)(r >> 7) * 131072 + (size_t)(k >> 6) * 8192 + ((r >> 6) & 1) * 4096 +
         ((k >> 5) & 1) * 2048 + ((r >> 4) & 3) * 512 + (((k >> 3) & 3) * 16 + (r & 15)) * 8 +
         (k & 7);
}

// ---------------- fused pack kernel ----------------
__device__ __forceinline__ void fragpack_chunk(const float* __restrict__ src,
                                               unsigned short* __restrict__ dst, int c) {
  const int lane = c & 63, m = (c >> 6) & 3, kk = (c >> 8) & 1, wr = (c >> 9) & 1,
            t = (c >> 10) & 15, panel = c >> 14;
  const int row = panel * 128 + wr * 64 + m * 16 + (lane & 15);
  const int k = t * 64 + kk * 32 + (lane >> 4) * 8;
  const float* s = src + (size_t)row * 1024 + k;
  const float4 v0 = *(const float4*)s;
  const float4 v1 = *(const float4*)(s + 4);
  ushort4 o0, o1;
  o0.x = f2bf(v0.x); o0.y = f2bf(v0.y); o0.z = f2bf(v0.z); o0.w = f2bf(v0.w);
  o1.x = f2bf(v1.x); o1.y = f2bf(v1.y); o1.z = f2bf(v1.z); o1.w = f2bf(v1.w);
  *(ushort4*)(dst + (size_t)c * 8) = o0;
  *(ushort4*)(dst + (size_t)c * 8 + 4) = o1;
}

__global__ void pack_fused(const float* __restrict__ x, const float* __restrict__ wq,
                           const float* __restrict__ wp, const float* __restrict__ prompt,
                           unsigned short* __restrict__ xd, unsigned short* __restrict__ wqd,
                           unsigned short* __restrict__ wpd, unsigned short* __restrict__ Kf,
                           unsigned short* __restrict__ Vf, const float* __restrict__ alpha) {
  int gid = blockIdx.x * 256 + threadIdx.x;
  if (gid < 1048576) {                       // x: 8192x1024
    fragpack_chunk(x, xd, gid);
  } else if (gid < 1441792) {                // Wqkv: 3072x1024
    fragpack_chunk(wq, wqd, gid - 1048576);
  } else if (gid < 1572864) {                // Wproj: 1024x1024
    fragpack_chunk(wp, wpd, gid - 1441792);
  } else {                                   // prompt prefix (t=0 tiles of K/V frag layout)
    int i = gid - 1572864;                   // 131072
    float a = alpha[0];
    int d4 = i & 15, p = (i >> 4) & 63, h = (i >> 10) & 15, b = i >> 14;
    const int bh = b * 16 + h;
    const int d0 = d4 * 4;
    const float4 kv4 = *(const float4*)(prompt + ((((size_t)(b * 2 + 0) * NP + p) * NH + h) * NHD + d0));
    {
      const int mk = p >> 4, lrk = p & 15, kk = d0 >> 5, lg = (d0 >> 3) & 3, e0 = d0 & 7;
      unsigned short* kd = Kf + (size_t)bh * BHSZ + ((mk * 2 + kk) * 4 + lg) * 128 + lrk * 8 + e0;
      kd[0] = f2bf(kv4.x * a); kd[1] = f2bf(kv4.y * a);
      kd[2] = f2bf(kv4.z * a); kd[3] = f2bf(kv4.w * a);
    }
    const float4 vv4 = *(const float4*)(prompt + ((((size_t)(b * 2 + 1) * NP + p) * NH + h) * NHD + d0));
    {
      const int df = d0 >> 4, kk = p >> 5, lg = (p >> 3) & 3, e = p & 7;
      unsigned short* vd = Vf + (size_t)bh * BHSZ + ((df * 2 + kk) * 4 + lg) * 128 + e;
      vd[((d0 + 0) & 15) * 8] = f2bf(vv4.x * a);
      vd[((d0 + 1) & 15) * 8] = f2bf(vv4.y * a);
      vd[((d0 + 2) & 15) * 8] = f2bf(vv4.z * a);
      vd[((d0 + 3) & 15) * 8] = f2bf(vv4.w * a);
    }
  }
}

// ---------------- direct-streaming GEMM: TLP version (64x32 wave-tile, 4 waves/SIMD) ----
// 512 thr = 8 waves (wm = wv>>2 in 0..1, wn = wv&3 in 0..3); block-tile 128x128.
// Per wave: acc 32 AGPR + 2 half-K frag buffers (24 VGPR each) + addr ~25 -> ~105 regs
// < 128 cliff -> 4 waves/SIMD (m69 allocation steps). Latency hidden by TLP.
template <int MODE>
__global__ __launch_bounds__(512, 4)
void gemm_direct(const unsigned short* __restrict__ Af, const unsigned short* __restrict__ Bf,
                 unsigned short* __restrict__ Qg, unsigned short* __restrict__ Kf,
                 unsigned short* __restrict__ Vf,
                 const float* __restrict__ alphap, const float* __restrict__ halfp,
                 float* __restrict__ Cout, const float* __restrict__ bias) {
  const int tid = threadIdx.x, lane = tid & 63, wv = tid >> 6;
  const int wm = wv >> 2, wn = wv & 3;
  const int lg = lane >> 4, lr = lane & 15;
  const int bx = blockIdx.x, by = blockIdx.y;

  // frag-packed bases: A(t,kk,m) = Abase + t*8192 + kk*2048 + m*512
  //                    B(t,kk,n) = Bbase + t*8192 + kk*2048 + n*512
  const unsigned short* Abase = Af + (size_t)bx * 131072 + wm * 4096 + lane * 8;
  const unsigned short* Bbase = Bf + (size_t)by * 131072 + (wn >> 1) * 4096 + (wn & 1) * 1024 + lane * 8;

  f32x4 acc[4][2] = {};
  bf16x8 xa[4], xb[2], ya[4], yb[2];

#define ISSUE(pa, pb, t, kk)                                                   \
  do {                                                                         \
    _Pragma("unroll") for (int m = 0; m < 4; ++m)                              \
        pa[m] = *(const bf16x8*)(Abase + (size_t)(t) * 8192 + (kk) * 2048 + m * 512); \
    _Pragma("unroll") for (int n = 0; n < 2; ++n)                              \
        pb[n] = *(const bf16x8*)(Bbase + (size_t)(t) * 8192 + (kk) * 2048 + n * 512); \
  } while (0)

#define MM(pa, pb)                                                             \
  do {                                                                         \
    __builtin_amdgcn_s_setprio(1);                                             \
    _Pragma("unroll") for (int m = 0; m < 4; ++m)                              \
    _Pragma("unroll") for (int n = 0; n < 2; ++n)                              \
        acc[m][n] = mfma16(pa[m], pb[n], acc[m][n]);                           \
    __builtin_amdgcn_s_setprio(0);                                             \
  } while (0)

  ISSUE(xa, xb, 0, 0);
  ISSUE(ya, yb, 0, 1);
#pragma unroll
  for (int s = 0; s < 32; ++s) {
    const int t2 = (s + 2) >> 1, k2 = (s + 2) & 1;
    if ((s & 1) == 0) {
      MM(xa, xb);
      if (s + 2 < 32) ISSUE(xa, xb, t2, k2);
    } else {
      MM(ya, yb);
      if (s + 2 < 32) ISSUE(ya, yb, t2, k2);
    }
  }
#undef ISSUE
#undef MM

  if constexpr (MODE == 0) {
    const int slot = (by * 128) >> 10;
    const int csIn = (by * 128) & 1023;
    // Q gets softmax scale folded in base-2 domain: 0.125 * log2(e)
    const float sc = (slot == 0) ? 0.18033688011112042f : (alphap[0] * halfp[0]);
#pragma unroll
    for (int m = 0; m < 4; ++m) {
      const int grow0 = bx * 128 + wm * 64 + m * 16 + lg * 4;
#pragma unroll
      for (int n = 0; n < 2; ++n) {
        const int gcol = csIn + wn * 32 + n * 16 + lr;
        const int h = gcol >> 6, d = gcol & 63;
#pragma unroll
        for (int j = 0; j < 4; ++j) {
          const int grow = grow0 + j;
          const int b = grow >> 10, nn = grow & 1023;
          const int bh = b * 16 + h;
          const unsigned short u = f2bf(acc[m][n][j] * sc);
          if (slot == 0) {
            Qg[((size_t)bh * NSEQ + nn) * NHD + d] = u;
          } else if (slot == 1) {
            const int kv = NP + nn;
            const int t = kv >> 6, mk = (kv >> 4) & 3, lrk = kv & 15;
            const int kkk = d >> 5, lgk = (d >> 3) & 3, e = d & 7;
            Kf[(size_t)bh * BHSZ + (size_t)((t * 4 + mk) * 2 + kkk) * 512 + (lgk * 16 + lrk) * 8 + e] = u;
          } else {
            const int kv = NP + nn;
            const int t = kv >> 6, kkv = (kv >> 5) & 1, lgv = (kv >> 3) & 3, e = kv & 7;
            const int df = d >> 4, lrv = d & 15;
            Vf[(size_t)bh * BHSZ + (size_t)((t * 4 + df) * 2 + kkv) * 512 + (lgv * 16 + lrv) * 8 + e] = u;
          }
        }
      }
    }
  } else {
#pragma unroll
    for (int m = 0; m < 4; ++m) {
      const int grow0 = bx * 128 + wm * 64 + m * 16 + lg * 4;
#pragma unroll
      for (int n = 0; n < 2; ++n) {
        const int gcol = by * 128 + wn * 32 + n * 16 + lr;
        const float bb = bias[gcol];
#pragma unroll
        for (int j = 0; j < 4; ++j)
          Cout[(size_t)(grow0 + j) * NC + gcol] = acc[m][n][j] + bb;
      }
    }
  }
}

// ---------------- flash attention: barrier-free, frag-direct K/V streaming ----------
__global__ __launch_bounds__(256, 3)
void attn_fwd(const unsigned short* __restrict__ Qg, const unsigned short* __restrict__ Kf,
              const unsigned short* __restrict__ Vf, unsigned short* __restrict__ Oat) {
  __shared__ __align__(16) unsigned short Plds[4 * 32 * 64];
  const int tid = threadIdx.x, lane = tid & 63, wv = tid >> 6;
  const int bh = blockIdx.x & 127;
  const int q0 = (blockIdx.x >> 7) * 128;
  const int lg = lane >> 4, lr = lane & 15;

  bf16x8 bq[2][2];
#pragma unroll
  for (int nq = 0; nq < 2; ++nq)
#pragma unroll
    for (int kk = 0; kk < 2; ++kk)
      bq[nq][kk] = *(const bf16x8*)(Qg + ((size_t)bh * NSEQ + q0 + wv * 32 + nq * 16 + lr) * NHD + kk * 32 + lg * 8);

  f32x4 oac[2][4] = {};
  float mrun[2] = {-1e30f, -1e30f};
  float lrun[2] = {0.f, 0.f};

  const unsigned short* Kb = Kf + (size_t)bh * BHSZ + lane * 8;
  const unsigned short* Vb = Vf + (size_t)bh * BHSZ + lane * 8;
  unsigned short* Pw = Plds + wv * 2048;

  for (int t = 0; t < 17; ++t) {
    bf16x8 ak[4][2];
#pragma unroll
    for (int mk = 0; mk < 4; ++mk)
#pragma unroll
      for (int kk = 0; kk < 2; ++kk)
        ak[mk][kk] = *(const bf16x8*)(Kb + (size_t)((t * 4 + mk) * 2 + kk) * 512);

    f32x4 sa[4][2] = {};
    __builtin_amdgcn_s_setprio(1);
#pragma unroll
    for (int kk = 0; kk < 2; ++kk)
#pragma unroll
      for (int mk = 0; mk < 4; ++mk)
#pragma unroll
        for (int nq = 0; nq < 2; ++nq)
          sa[mk][nq] = mfma16(ak[mk][kk], bq[nq][kk], sa[mk][nq]);
    __builtin_amdgcn_s_setprio(0);

    bf16x8 bv[4][2];
#pragma unroll
    for (int df = 0; df < 4; ++df)
#pragma unroll
      for (int kk = 0; kk < 2; ++kk)
        bv[df][kk] = *(const bf16x8*)(Vb + (size_t)((t * 4 + df) * 2 + kk) * 512);

    float tmx[2];
#pragma unroll
    for (int nq = 0; nq < 2; ++nq) {
      f32x4 m4 = sa[0][nq];
#pragma unroll
      for (int mk = 1; mk < 4; ++mk)
#pragma unroll
        for (int j = 0; j < 4; ++j) m4[j] = fmaxf(m4[j], sa[mk][nq][j]);
      float tm = fmaxf(fmaxf(m4[0], m4[1]), fmaxf(m4[2], m4[3]));
      tm = fmaxf(tm, __shfl_xor(tm, 16));
      tm = fmaxf(tm, __shfl_xor(tm, 32));
      tmx[nq] = tm;
    }
    const bool upd = !__all((tmx[0] <= mrun[0] + 8.f) && (tmx[1] <= mrun[1] + 8.f));
    if (upd) {
      const float nm0 = fmaxf(mrun[0], tmx[0]);
      const float nm1 = fmaxf(mrun[1], tmx[1]);
      const float e0 = __builtin_amdgcn_exp2f(mrun[0] - nm0);
      const float e1 = __builtin_amdgcn_exp2f(mrun[1] - nm1);
      mrun[0] = nm0; mrun[1] = nm1;
      lrun[0] *= e0; lrun[1] *= e1;
#pragma unroll
      for (int m = 0; m < 2; ++m)
#pragma unroll
        for (int j = 0; j < 4; ++j) {
          const float fe = __shfl(m ? e1 : e0, lg * 4 + j, 16);
#pragma unroll
          for (int df = 0; df < 4; ++df) oac[m][df][j] *= fe;
        }
    }
#pragma unroll
    for (int nq = 0; nq < 2; ++nq) {
#pragma unroll
      for (int mk = 0; mk < 4; ++mk)
#pragma unroll
        for (int j = 0; j < 4; ++j)
          sa[mk][nq][j] = __builtin_amdgcn_exp2f(sa[mk][nq][j] - mrun[nq]);
      f32x4 s4 = sa[0][nq];
#pragma unroll
      for (int mk = 1; mk < 4; ++mk)
#pragma unroll
        for (int j = 0; j < 4; ++j) s4[j] += sa[mk][nq][j];
      float s = (s4[0] + s4[1]) + (s4[2] + s4[3]);
      s += __shfl_xor(s, 16);
      s += __shfl_xor(s, 32);
      lrun[nq] += s;
      const int q = nq * 16 + lr;
#pragma unroll
      for (int mk = 0; mk < 4; ++mk) {
        const int c = mk * 2 + (lg >> 1);
        uint2 uu;
        uu.x = (unsigned)f2bf(sa[mk][nq][0]) | ((unsigned)f2bf(sa[mk][nq][1]) << 16);
        uu.y = (unsigned)f2bf(sa[mk][nq][2]) | ((unsigned)f2bf(sa[mk][nq][3]) << 16);
        *(uint2*)(Pw + q * 64 + ((c ^ (q & 7)) << 3) + (lg & 1) * 4) = uu;
      }
    }

    __builtin_amdgcn_s_setprio(1);
#pragma unroll
    for (int kk = 0; kk < 2; ++kk) {
      bf16x8 ap[2];
#pragma unroll
      for (int m = 0; m < 2; ++m) {
        const int q = m * 16 + lr;
        const int pos = (kk * 4 + lg) ^ (q & 7);
        ap[m] = *(const bf16x8*)(Pw + q * 64 + pos * 8);
      }
#pragma unroll
      for (int m = 0; m < 2; ++m)
#pragma unroll
        for (int df = 0; df < 4; ++df)
          oac[m][df] = mfma16(ap[m], bv[df][kk], oac[m][df]);
    }
    __builtin_amdgcn_s_setprio(0);
  }

  // epilogue: write O fragment-packed (proj-A layout) so gemm_direct<1> streams it
  const int bidx = bh >> 4, h = bh & 15;
  const float l0 = 1.f / lrun[0], l1 = 1.f / lrun[1];
#pragma unroll
  for (int m = 0; m < 2; ++m) {
#pragma unroll
    for (int j = 0; j < 4; ++j) {
      const float fi = __shfl(m ? l1 : l0, lg * 4 + j, 16);
      const int grow = bidx * NSEQ + q0 + wv * 32 + m * 16 + lg * 4 + j;
#pragma unroll
      for (int df = 0; df < 4; ++df) {
        const int col = h * 64 + df * 16 + lr;
        Oat[fa_elem(grow, col)] = f2bf(oac[m][df][j] * fi);
      }
    }
  }
}

// ---------------- launch ----------------
extern "C" void kernel_launch(void* const* d_in, const int* in_sizes, int n_in,
                              void* d_out, int out_size, void* d_ws, size_t ws_size,
                              hipStream_t stream) {
  const float* x      = (const float*)d_in[0];
  const float* prompt = (const float*)d_in[1];
  const float* alpha  = (const float*)d_in[2];
  const float* halfa  = (const float*)d_in[3];
  const float* Wqkv   = (const float*)d_in[4];
  const float* Wproj  = (const float*)d_in[5];
  const float* bproj  = (const float*)d_in[6];
  float* out = (float*)d_out;

  unsigned short* ws    = (unsigned short*)d_ws;
  unsigned short* x_bf  = ws;                                  // frag-packed
  unsigned short* w_bf  = x_bf + (size_t)8192 * 1024;          // frag-packed
  unsigned short* wp_bf = w_bf + (size_t)3072 * 1024;          // frag-packed
  unsigned short* Qg    = wp_bf + (size_t)1024 * 1024;         // row-major
  unsigned short* Kf    = Qg + (size_t)NB * NH * NSEQ * NHD;   // attn-frag-packed
  unsigned short* Vf    = Kf + (size_t)128 * BHSZ;             // attn-frag-packed
  unsigned short* Oat   = Vf + (size_t)128 * BHSZ;             // frag-packed

  pack_fused<<<6656, 256, 0, stream>>>(x, Wqkv, Wproj, prompt, x_bf, w_bf, wp_bf,
                                       Kf, Vf, alpha);

  // QKV: M=8192 N=3072 -> 64 x 24 of 128^2, TLP direct streaming (512 thr)
  gemm_direct<0><<<dim3(64, 24), 512, 0, stream>>>(x_bf, w_bf, Qg, Kf, Vf, alpha, halfa,
                                                   nullptr, nullptr);
  attn_fwd<<<1024, 256, 0, stream>>>(Qg, Kf, Vf, Oat);
  // proj: M=8192 N=1024 -> 64 x 8 of 128^2, TLP direct streaming (512 thr)
  gemm_direct<1><<<dim3(64, 8), 512, 0, stream>>>(Oat, wp_bf, nullptr, nullptr, nullptr,
                                                  nullptr, nullptr, out, bproj);
}

// Round 14
// 157.815 us; speedup vs baseline: 1.2096x; 1.2096x over previous
//
#include <hip/hip_runtime.h>

typedef float f32x4 __attribute__((ext_vector_type(4)));
typedef short bf16x8 __attribute__((ext_vector_type(8)));

#define NB 8
#define NH 16
#define NSEQ 1024
#define NP 64
#define NKV 1088
#define NC 1024
#define NHD 64
#define BHSZ 69632  // per-(b,h) K/V fragment-packed size = 1088*64

__device__ __forceinline__ unsigned short f2bf(float f) {
  unsigned int u = __builtin_bit_cast(unsigned int, f);
  u += 0x7fffu + ((u >> 16) & 1u);  // RNE
  return (unsigned short)(u >> 16);
}

__device__ __forceinline__ f32x4 mfma16(bf16x8 a, bf16x8 b, f32x4 c) {
  return __builtin_amdgcn_mfma_f32_16x16x32_bf16(a, b, c, 0, 0, 0);
}

// fragment-packed address (element granularity) for a row-major [R][1024] matrix
// (GEMM A/B operands). row = panel*128 + half*64 + m*16 + lr ; k = t*64 + kk*32 + lg*8 + e
__device__ __forceinline__ size_t fa_elem(int r, int k) {
  return (size_t)(r >> 7) * 131072 + (size_t)(k >> 6) * 8192 + ((r >> 6) & 1) * 4096 +
         ((k >> 5) & 1) * 2048 + ((r >> 4) & 3) * 512 + (((k >> 3) & 3) * 16 + (r & 15)) * 8 +
         (k & 7);
}

// ---------------- fused pack kernel ----------------
__device__ __forceinline__ void fragpack_chunk(const float* __restrict__ src,
                                               unsigned short* __restrict__ dst, int c) {
  const int lane = c & 63, m = (c >> 6) & 3, kk = (c >> 8) & 1, wr = (c >> 9) & 1,
            t = (c >> 10) & 15, panel = c >> 14;
  const int row = panel * 128 + wr * 64 + m * 16 + (lane & 15);
  const int k = t * 64 + kk * 32 + (lane >> 4) * 8;
  const float* s = src + (size_t)row * 1024 + k;
  const float4 v0 = *(const float4*)s;
  const float4 v1 = *(const float4*)(s + 4);
  ushort4 o0, o1;
  o0.x = f2bf(v0.x); o0.y = f2bf(v0.y); o0.z = f2bf(v0.z); o0.w = f2bf(v0.w);
  o1.x = f2bf(v1.x); o1.y = f2bf(v1.y); o1.z = f2bf(v1.z); o1.w = f2bf(v1.w);
  *(ushort4*)(dst + (size_t)c * 8) = o0;
  *(ushort4*)(dst + (size_t)c * 8 + 4) = o1;
}

__global__ void pack_fused(const float* __restrict__ x, const float* __restrict__ wq,
                           const float* __restrict__ wp, const float* __restrict__ prompt,
                           unsigned short* __restrict__ xd, unsigned short* __restrict__ wqd,
                           unsigned short* __restrict__ wpd, unsigned short* __restrict__ Kf,
                           unsigned short* __restrict__ Vf, const float* __restrict__ alpha) {
  int gid = blockIdx.x * 256 + threadIdx.x;
  if (gid < 1048576) {                       // x: 8192x1024
    fragpack_chunk(x, xd, gid);
  } else if (gid < 1441792) {                // Wqkv: 3072x1024
    fragpack_chunk(wq, wqd, gid - 1048576);
  } else if (gid < 1572864) {                // Wproj: 1024x1024
    fragpack_chunk(wp, wpd, gid - 1441792);
  } else {                                   // prompt prefix (t=0 tiles of K/V frag layout)
    int i = gid - 1572864;                   // 131072
    float a = alpha[0];
    int d4 = i & 15, p = (i >> 4) & 63, h = (i >> 10) & 15, b = i >> 14;
    const int bh = b * 16 + h;
    const int d0 = d4 * 4;
    const float4 kv4 = *(const float4*)(prompt + ((((size_t)(b * 2 + 0) * NP + p) * NH + h) * NHD + d0));
    {
      const int mk = p >> 4, lrk = p & 15, kk = d0 >> 5, lg = (d0 >> 3) & 3, e0 = d0 & 7;
      unsigned short* kd = Kf + (size_t)bh * BHSZ + ((mk * 2 + kk) * 4 + lg) * 128 + lrk * 8 + e0;
      kd[0] = f2bf(kv4.x * a); kd[1] = f2bf(kv4.y * a);
      kd[2] = f2bf(kv4.z * a); kd[3] = f2bf(kv4.w * a);
    }
    const float4 vv4 = *(const float4*)(prompt + ((((size_t)(b * 2 + 1) * NP + p) * NH + h) * NHD + d0));
    {
      const int df = d0 >> 4, kk = p >> 5, lg = (p >> 3) & 3, e = p & 7;
      unsigned short* vd = Vf + (size_t)bh * BHSZ + ((df * 2 + kk) * 4 + lg) * 128 + e;
      vd[((d0 + 0) & 15) * 8] = f2bf(vv4.x * a);
      vd[((d0 + 1) & 15) * 8] = f2bf(vv4.y * a);
      vd[((d0 + 2) & 15) * 8] = f2bf(vv4.z * a);
      vd[((d0 + 3) & 15) * 8] = f2bf(vv4.w * a);
    }
  }
}

// ---------------- QKV GEMM: 64x128 wave-tile direct streaming (L1-intensity fix) ------
// 256 thr = 4 waves stacked in M (block tile 256x128); all waves share B frags.
// bytes/MFMA = 1024*(4+8)/(4*8) = 384 (vs 512 at 64x64) -> -25% L1 demand.
// acc 32 f32x4 (AGPR) + 2 half-K frag buffers (12 bf16x8 each) -> ~240 regs, 2 waves/SIMD.
__global__ __launch_bounds__(256, 2)
void gemm_qkv_w(const unsigned short* __restrict__ Af, const unsigned short* __restrict__ Bf,
                unsigned short* __restrict__ Qg, unsigned short* __restrict__ Kf,
                unsigned short* __restrict__ Vf,
                const float* __restrict__ alphap, const float* __restrict__ halfp) {
  const int tid = threadIdx.x, lane = tid & 63, wv = tid >> 6;
  const int lg = lane >> 4, lr = lane & 15;
  const int bx = blockIdx.x, by = blockIdx.y;  // 32 x 24

  // A rows: bx*256 + wv*64 -> fa panel bx*2 + (wv>>1), half (wv&1)
  const unsigned short* Abase = Af + (size_t)(bx * 2 + (wv >> 1)) * 131072 + (wv & 1) * 4096 + lane * 8;
  // B rows (= out cols): by*128 -> fa panel by; frag n: half n>>2, sub n&3
  const unsigned short* Bbase = Bf + (size_t)by * 131072 + lane * 8;

  f32x4 acc[4][8] = {};
  bf16x8 xa[4], xb[8], ya[4], yb[8];

#define ISSUE(pa, pb, t, kk)                                                       \
  do {                                                                             \
    _Pragma("unroll") for (int m = 0; m < 4; ++m)                                  \
        pa[m] = *(const bf16x8*)(Abase + (size_t)(t) * 8192 + (kk) * 2048 + m * 512); \
    _Pragma("unroll") for (int n = 0; n < 8; ++n)                                  \
        pb[n] = *(const bf16x8*)(Bbase + (size_t)(t) * 8192 + (kk) * 2048 +        \
                                 (n >> 2) * 4096 + (n & 3) * 512);                 \
  } while (0)

#define MM(pa, pb)                                                                 \
  do {                                                                             \
    __builtin_amdgcn_s_setprio(1);                                                 \
    _Pragma("unroll") for (int m = 0; m < 4; ++m)                                  \
    _Pragma("unroll") for (int n = 0; n < 8; ++n)                                  \
        acc[m][n] = mfma16(pa[m], pb[n], acc[m][n]);                               \
    __builtin_amdgcn_s_setprio(0);                                                 \
  } while (0)

  ISSUE(xa, xb, 0, 0);
  ISSUE(ya, yb, 0, 1);
#pragma unroll
  for (int s = 0; s < 32; ++s) {
    const int t2 = (s + 2) >> 1, k2 = (s + 2) & 1;
    if ((s & 1) == 0) {
      MM(xa, xb);
      if (s + 2 < 32) ISSUE(xa, xb, t2, k2);
    } else {
      MM(ya, yb);
      if (s + 2 < 32) ISSUE(ya, yb, t2, k2);
    }
  }
#undef ISSUE
#undef MM

  // epilogue: scatter to Q / K(+64) / V^T(+64)
  const int slot = by >> 3;              // 8 by-panels (1024 cols) per slot
  const int csIn = (by & 7) * 128;
  const float sc = (slot == 0) ? 0.18033688011112042f : (alphap[0] * halfp[0]);
#pragma unroll
  for (int m = 0; m < 4; ++m) {
    const int grow0 = bx * 256 + wv * 64 + m * 16 + lg * 4;
#pragma unroll
    for (int n = 0; n < 8; ++n) {
      const int gcol = csIn + n * 16 + lr;
      const int h = gcol >> 6, d = gcol & 63;
#pragma unroll
      for (int j = 0; j < 4; ++j) {
        const int grow = grow0 + j;
        const int b = grow >> 10, nn = grow & 1023;
        const int bh = b * 16 + h;
        const unsigned short u = f2bf(acc[m][n][j] * sc);
        if (slot == 0) {
          Qg[((size_t)bh * NSEQ + nn) * NHD + d] = u;
        } else if (slot == 1) {
          const int kv = NP + nn;
          const int t = kv >> 6, mk = (kv >> 4) & 3, lrk = kv & 15;
          const int kkk = d >> 5, lgk = (d >> 3) & 3, e = d & 7;
          Kf[(size_t)bh * BHSZ + (size_t)((t * 4 + mk) * 2 + kkk) * 512 + (lgk * 16 + lrk) * 8 + e] = u;
        } else {
          const int kv = NP + nn;
          const int t = kv >> 6, kkv = (kv >> 5) & 1, lgv = (kv >> 3) & 3, e = kv & 7;
          const int df = d >> 4, lrv = d & 15;
          Vf[(size_t)bh * BHSZ + (size_t)((t * 4 + df) * 2 + kkv) * 512 + (lgv * 16 + lrv) * 8 + e] = u;
        }
      }
    }
  }
}

// ---------------- proj GEMM (r11-proven: 64x64 wave-tile, 2-deep, no LDS) ----------
__global__ __launch_bounds__(256, 2)
void gemm_proj(const unsigned short* __restrict__ Af, const unsigned short* __restrict__ Bf,
               float* __restrict__ Cout, const float* __restrict__ bias) {
  const int tid = threadIdx.x, lane = tid & 63, wv = tid >> 6;
  const int wr = wv >> 1, wc = wv & 1;
  const int lg = lane >> 4, lr = lane & 15;
  const int bx = blockIdx.x, by = blockIdx.y;

  const unsigned short* Ab = Af + (size_t)bx * 131072 + wr * 4096 + lane * 8;
  const unsigned short* Bb = Bf + (size_t)by * 131072 + wc * 4096 + lane * 8;

  f32x4 acc[4][4] = {};
  bf16x8 aC[2][4], bC[2][4], aN[2][4], bN[2][4];

#define LOADA(dst, t)                                                          \
  _Pragma("unroll") for (int kk = 0; kk < 2; ++kk)                             \
  _Pragma("unroll") for (int m = 0; m < 4; ++m)                                \
      dst[kk][m] = *(const bf16x8*)(Ab + (size_t)(t) * 8192 + kk * 2048 + m * 512)
#define LOADB(dst, t)                                                          \
  _Pragma("unroll") for (int kk = 0; kk < 2; ++kk)                             \
  _Pragma("unroll") for (int n = 0; n < 4; ++n)                                \
      dst[kk][n] = *(const bf16x8*)(Bb + (size_t)(t) * 8192 + kk * 2048 + n * 512)

  LOADA(aC, 0);
  LOADB(bC, 0);
#pragma unroll
  for (int t = 0; t < 16; ++t) {
    if (t < 15) { LOADA(aN, t + 1); LOADB(bN, t + 1); }
    __builtin_amdgcn_s_setprio(1);
#pragma unroll
    for (int kk = 0; kk < 2; ++kk)
#pragma unroll
      for (int m = 0; m < 4; ++m)
#pragma unroll
        for (int n = 0; n < 4; ++n)
          acc[m][n] = mfma16(aC[kk][m], bC[kk][n], acc[m][n]);
    __builtin_amdgcn_s_setprio(0);
#pragma unroll
    for (int kk = 0; kk < 2; ++kk)
#pragma unroll
      for (int i = 0; i < 4; ++i) { aC[kk][i] = aN[kk][i]; bC[kk][i] = bN[kk][i]; }
  }
#undef LOADA
#undef LOADB

#pragma unroll
  for (int m = 0; m < 4; ++m) {
    const int grow0 = bx * 128 + wr * 64 + m * 16 + lg * 4;
#pragma unroll
    for (int n = 0; n < 4; ++n) {
      const int gcol = by * 128 + wc * 64 + n * 16 + lr;
      const float bb = bias[gcol];
#pragma unroll
      for (int j = 0; j < 4; ++j)
        Cout[(size_t)(grow0 + j) * NC + gcol] = acc[m][n][j] + bb;
    }
  }
}

// ---------------- flash attention: barrier-free, frag-direct K/V streaming ----------
__global__ __launch_bounds__(256, 3)
void attn_fwd(const unsigned short* __restrict__ Qg, const unsigned short* __restrict__ Kf,
              const unsigned short* __restrict__ Vf, unsigned short* __restrict__ Oat) {
  __shared__ __align__(16) unsigned short Plds[4 * 32 * 64];
  const int tid = threadIdx.x, lane = tid & 63, wv = tid >> 6;
  const int bh = blockIdx.x & 127;
  const int q0 = (blockIdx.x >> 7) * 128;
  const int lg = lane >> 4, lr = lane & 15;

  bf16x8 bq[2][2];
#pragma unroll
  for (int nq = 0; nq < 2; ++nq)
#pragma unroll
    for (int kk = 0; kk < 2; ++kk)
      bq[nq][kk] = *(const bf16x8*)(Qg + ((size_t)bh * NSEQ + q0 + wv * 32 + nq * 16 + lr) * NHD + kk * 32 + lg * 8);

  f32x4 oac[2][4] = {};
  float mrun[2] = {-1e30f, -1e30f};
  float lrun[2] = {0.f, 0.f};

  const unsigned short* Kb = Kf + (size_t)bh * BHSZ + lane * 8;
  const unsigned short* Vb = Vf + (size_t)bh * BHSZ + lane * 8;
  unsigned short* Pw = Plds + wv * 2048;

  for (int t = 0; t < 17; ++t) {
    bf16x8 ak[4][2];
#pragma unroll
    for (int mk = 0; mk < 4; ++mk)
#pragma unroll
      for (int kk = 0; kk < 2; ++kk)
        ak[mk][kk] = *(const bf16x8*)(Kb + (size_t)((t * 4 + mk) * 2 + kk) * 512);

    f32x4 sa[4][2] = {};
    __builtin_amdgcn_s_setprio(1);
#pragma unroll
    for (int kk = 0; kk < 2; ++kk)
#pragma unroll
      for (int mk = 0; mk < 4; ++mk)
#pragma unroll
        for (int nq = 0; nq < 2; ++nq)
          sa[mk][nq] = mfma16(ak[mk][kk], bq[nq][kk], sa[mk][nq]);
    __builtin_amdgcn_s_setprio(0);

    bf16x8 bv[4][2];
#pragma unroll
    for (int df = 0; df < 4; ++df)
#pragma unroll
      for (int kk = 0; kk < 2; ++kk)
        bv[df][kk] = *(const bf16x8*)(Vb + (size_t)((t * 4 + df) * 2 + kk) * 512);

    float tmx[2];
#pragma unroll
    for (int nq = 0; nq < 2; ++nq) {
      f32x4 m4 = sa[0][nq];
#pragma unroll
      for (int mk = 1; mk < 4; ++mk)
#pragma unroll
        for (int j = 0; j < 4; ++j) m4[j] = fmaxf(m4[j], sa[mk][nq][j]);
      float tm = fmaxf(fmaxf(m4[0], m4[1]), fmaxf(m4[2], m4[3]));
      tm = fmaxf(tm, __shfl_xor(tm, 16));
      tm = fmaxf(tm, __shfl_xor(tm, 32));
      tmx[nq] = tm;
    }
    const bool upd = !__all((tmx[0] <= mrun[0] + 8.f) && (tmx[1] <= mrun[1] + 8.f));
    if (upd) {
      const float nm0 = fmaxf(mrun[0], tmx[0]);
      const float nm1 = fmaxf(mrun[1], tmx[1]);
      const float e0 = __builtin_amdgcn_exp2f(mrun[0] - nm0);
      const float e1 = __builtin_amdgcn_exp2f(mrun[1] - nm1);
      mrun[0] = nm0; mrun[1] = nm1;
      lrun[0] *= e0; lrun[1] *= e1;
#pragma unroll
      for (int m = 0; m < 2; ++m)
#pragma unroll
        for (int j = 0; j < 4; ++j) {
          const float fe = __shfl(m ? e1 : e0, lg * 4 + j, 16);
#pragma unroll
          for (int df = 0; df < 4; ++df) oac[m][df][j] *= fe;
        }
    }
#pragma unroll
    for (int nq = 0; nq < 2; ++nq) {
#pragma unroll
      for (int mk = 0; mk < 4; ++mk)
#pragma unroll
        for (int j = 0; j < 4; ++j)
          sa[mk][nq][j] = __builtin_amdgcn_exp2f(sa[mk][nq][j] - mrun[nq]);
      f32x4 s4 = sa[0][nq];
#pragma unroll
      for (int mk = 1; mk < 4; ++mk)
#pragma unroll
        for (int j = 0; j < 4; ++j) s4[j] += sa[mk][nq][j];
      float s = (s4[0] + s4[1]) + (s4[2] + s4[3]);
      s += __shfl_xor(s, 16);
      s += __shfl_xor(s, 32);
      lrun[nq] += s;
      const int q = nq * 16 + lr;
#pragma unroll
      for (int mk = 0; mk < 4; ++mk) {
        const int c = mk * 2 + (lg >> 1);
        uint2 uu;
        uu.x = (unsigned)f2bf(sa[mk][nq][0]) | ((unsigned)f2bf(sa[mk][nq][1]) << 16);
        uu.y = (unsigned)f2bf(sa[mk][nq][2]) | ((unsigned)f2bf(sa[mk][nq][3]) << 16);
        *(uint2*)(Pw + q * 64 + ((c ^ (q & 7)) << 3) + (lg & 1) * 4) = uu;
      }
    }

    __builtin_amdgcn_s_setprio(1);
#pragma unroll
    for (int kk = 0; kk < 2; ++kk) {
      bf16x8 ap[2];
#pragma unroll
      for (int m = 0; m < 2; ++m) {
        const int q = m * 16 + lr;
        const int pos = (kk * 4 + lg) ^ (q & 7);
        ap[m] = *(const bf16x8*)(Pw + q * 64 + pos * 8);
      }
#pragma unroll
      for (int m = 0; m < 2; ++m)
#pragma unroll
        for (int df = 0; df < 4; ++df)
          oac[m][df] = mfma16(ap[m], bv[df][kk], oac[m][df]);
    }
    __builtin_amdgcn_s_setprio(0);
  }

  // epilogue: write O fragment-packed (proj-A layout) so gemm_proj streams it
  const int bidx = bh >> 4, h = bh & 15;
  const float l0 = 1.f / lrun[0], l1 = 1.f / lrun[1];
#pragma unroll
  for (int m = 0; m < 2; ++m) {
#pragma unroll
    for (int j = 0; j < 4; ++j) {
      const float fi = __shfl(m ? l1 : l0, lg * 4 + j, 16);
      const int grow = bidx * NSEQ + q0 + wv * 32 + m * 16 + lg * 4 + j;
#pragma unroll
      for (int df = 0; df < 4; ++df) {
        const int col = h * 64 + df * 16 + lr;
        Oat[fa_elem(grow, col)] = f2bf(oac[m][df][j] * fi);
      }
    }
  }
}

// ---------------- launch ----------------
extern "C" void kernel_launch(void* const* d_in, const int* in_sizes, int n_in,
                              void* d_out, int out_size, void* d_ws, size_t ws_size,
                              hipStream_t stream) {
  const float* x      = (const float*)d_in[0];
  const float* prompt = (const float*)d_in[1];
  const float* alpha  = (const float*)d_in[2];
  const float* halfa  = (const float*)d_in[3];
  const float* Wqkv   = (const float*)d_in[4];
  const float* Wproj  = (const float*)d_in[5];
  const float* bproj  = (const float*)d_in[6];
  float* out = (float*)d_out;

  unsigned short* ws    = (unsigned short*)d_ws;
  unsigned short* x_bf  = ws;                                  // frag-packed
  unsigned short* w_bf  = x_bf + (size_t)8192 * 1024;          // frag-packed
  unsigned short* wp_bf = w_bf + (size_t)3072 * 1024;          // frag-packed
  unsigned short* Qg    = wp_bf + (size_t)1024 * 1024;         // row-major
  unsigned short* Kf    = Qg + (size_t)NB * NH * NSEQ * NHD;   // attn-frag-packed
  unsigned short* Vf    = Kf + (size_t)128 * BHSZ;             // attn-frag-packed
  unsigned short* Oat   = Vf + (size_t)128 * BHSZ;             // frag-packed

  pack_fused<<<6656, 256, 0, stream>>>(x, Wqkv, Wproj, prompt, x_bf, w_bf, wp_bf,
                                       Kf, Vf, alpha);

  // QKV: M=8192 N=3072 -> 32 x 24 blocks of 256x128 (64x128 wave-tile)
  gemm_qkv_w<<<dim3(32, 24), 256, 0, stream>>>(x_bf, w_bf, Qg, Kf, Vf, alpha, halfa);
  attn_fwd<<<1024, 256, 0, stream>>>(Qg, Kf, Vf, Oat);
  // proj: M=8192 N=1024 -> 64 x 8 of 128^2 (r11-proven 64x64 wave-tile)
  gemm_proj<<<dim3(64, 8), 256, 0, stream>>>(Oat, wp_bf, out, bproj);
}

// Round 16
// 152.533 us; speedup vs baseline: 1.2515x; 1.0346x over previous
//
#include <hip/hip_runtime.h>

typedef float f32x4 __attribute__((ext_vector_type(4)));
typedef short bf16x8 __attribute__((ext_vector_type(8)));

#define NB 8
#define NH 16
#define NSEQ 1024
#define NP 64
#define NKV 1088
#define NC 1024
#define NHD 64
#define BHSZ 69632  // per-(b,h) K/V fragment-packed size = 1088*64

__device__ __forceinline__ unsigned short f2bf(float f) {
  unsigned int u = __builtin_bit_cast(unsigned int, f);
  u += 0x7fffu + ((u >> 16) & 1u);  // RNE
  return (unsigned short)(u >> 16);
}

// packed pair conversion via v_cvt_pk_bf16_f32 (RNE): lo = a, hi = b
__device__ __forceinline__ unsigned pk2bf(float a, float b) {
  unsigned r;
  asm("v_cvt_pk_bf16_f32 %0, %1, %2" : "=v"(r) : "v"(a), "v"(b));
  return r;
}

__device__ __forceinline__ f32x4 mfma16(bf16x8 a, bf16x8 b, f32x4 c) {
  return __builtin_amdgcn_mfma_f32_16x16x32_bf16(a, b, c, 0, 0, 0);
}

// fragment-packed address (element granularity) for a row-major [R][1024] matrix
// (GEMM A/B operands). row = panel*128 + half*64 + m*16 + lr ; k = t*64 + kk*32 + lg*8 + e
__device__ __forceinline__ size_t fa_elem(int r, int k) {
  return (size_t)(r >> 7) * 131072 + (size_t)(k >> 6) * 8192 + ((r >> 6) & 1) * 4096 +
         ((k >> 5) & 1) * 2048 + ((r >> 4) & 3) * 512 + (((k >> 3) & 3) * 16 + (r & 15)) * 8 +
         (k & 7);
}

// ---------------- fused pack kernel ----------------
__device__ __forceinline__ void fragpack_chunk(const float* __restrict__ src,
                                               unsigned short* __restrict__ dst, int c) {
  const int lane = c & 63, m = (c >> 6) & 3, kk = (c >> 8) & 1, wr = (c >> 9) & 1,
            t = (c >> 10) & 15, panel = c >> 14;
  const int row = panel * 128 + wr * 64 + m * 16 + (lane & 15);
  const int k = t * 64 + kk * 32 + (lane >> 4) * 8;
  const float* s = src + (size_t)row * 1024 + k;
  const float4 v0 = *(const float4*)s;
  const float4 v1 = *(const float4*)(s + 4);
  ushort4 o0, o1;
  o0.x = f2bf(v0.x); o0.y = f2bf(v0.y); o0.z = f2bf(v0.z); o0.w = f2bf(v0.w);
  o1.x = f2bf(v1.x); o1.y = f2bf(v1.y); o1.z = f2bf(v1.z); o1.w = f2bf(v1.w);
  *(ushort4*)(dst + (size_t)c * 8) = o0;
  *(ushort4*)(dst + (size_t)c * 8 + 4) = o1;
}

__global__ void pack_fused(const float* __restrict__ x, const float* __restrict__ wq,
                           const float* __restrict__ wp, const float* __restrict__ prompt,
                           unsigned short* __restrict__ xd, unsigned short* __restrict__ wqd,
                           unsigned short* __restrict__ wpd, unsigned short* __restrict__ Kf,
                           unsigned short* __restrict__ Vf, const float* __restrict__ alpha) {
  int gid = blockIdx.x * 256 + threadIdx.x;
  if (gid < 1048576) {                       // x: 8192x1024
    fragpack_chunk(x, xd, gid);
  } else if (gid < 1441792) {                // Wqkv: 3072x1024
    fragpack_chunk(wq, wqd, gid - 1048576);
  } else if (gid < 1572864) {                // Wproj: 1024x1024
    fragpack_chunk(wp, wpd, gid - 1441792);
  } else {                                   // prompt prefix (t=0 tiles of K/V frag layout)
    int i = gid - 1572864;                   // 131072
    float a = alpha[0];
    int d4 = i & 15, p = (i >> 4) & 63, h = (i >> 10) & 15, b = i >> 14;
    const int bh = b * 16 + h;
    const int d0 = d4 * 4;
    const float4 kv4 = *(const float4*)(prompt + ((((size_t)(b * 2 + 0) * NP + p) * NH + h) * NHD + d0));
    {
      const int mk = p >> 4, lrk = p & 15, kk = d0 >> 5, lg = (d0 >> 3) & 3, e0 = d0 & 7;
      unsigned short* kd = Kf + (size_t)bh * BHSZ + ((mk * 2 + kk) * 4 + lg) * 128 + lrk * 8 + e0;
      kd[0] = f2bf(kv4.x * a); kd[1] = f2bf(kv4.y * a);
      kd[2] = f2bf(kv4.z * a); kd[3] = f2bf(kv4.w * a);
    }
    const float4 vv4 = *(const float4*)(prompt + ((((size_t)(b * 2 + 1) * NP + p) * NH + h) * NHD + d0));
    {
      const int df = d0 >> 4, kk = p >> 5, lg = (p >> 3) & 3, e = p & 7;
      unsigned short* vd = Vf + (size_t)bh * BHSZ + ((df * 2 + kk) * 4 + lg) * 128 + e;
      vd[((d0 + 0) & 15) * 8] = f2bf(vv4.x * a);
      vd[((d0 + 1) & 15) * 8] = f2bf(vv4.y * a);
      vd[((d0 + 2) & 15) * 8] = f2bf(vv4.z * a);
      vd[((d0 + 3) & 15) * 8] = f2bf(vv4.w * a);
    }
  }
}

// ---------------- QKV GEMM: 64x128 wave-tile direct streaming ------
__global__ __launch_bounds__(256, 2)
void gemm_qkv_w(const unsigned short* __restrict__ Af, const unsigned short* __restrict__ Bf,
                unsigned short* __restrict__ Qg, unsigned short* __restrict__ Kf,
                unsigned short* __restrict__ Vf,
                const float* __restrict__ alphap, const float* __restrict__ halfp) {
  const int tid = threadIdx.x, lane = tid & 63, wv = tid >> 6;
  const int lg = lane >> 4, lr = lane & 15;
  const int bx = blockIdx.x, by = blockIdx.y;  // 32 x 24

  const unsigned short* Abase = Af + (size_t)(bx * 2 + (wv >> 1)) * 131072 + (wv & 1) * 4096 + lane * 8;
  const unsigned short* Bbase = Bf + (size_t)by * 131072 + lane * 8;

  f32x4 acc[4][8] = {};
  bf16x8 xa[4], xb[8], ya[4], yb[8];

#define ISSUE(pa, pb, t, kk)                                                       \
  do {                                                                             \
    _Pragma("unroll") for (int m = 0; m < 4; ++m)                                  \
        pa[m] = *(const bf16x8*)(Abase + (size_t)(t) * 8192 + (kk) * 2048 + m * 512); \
    _Pragma("unroll") for (int n = 0; n < 8; ++n)                                  \
        pb[n] = *(const bf16x8*)(Bbase + (size_t)(t) * 8192 + (kk) * 2048 +        \
                                 (n >> 2) * 4096 + (n & 3) * 512);                 \
  } while (0)

#define MM(pa, pb)                                                                 \
  do {                                                                             \
    __builtin_amdgcn_s_setprio(1);                                                 \
    _Pragma("unroll") for (int m = 0; m < 4; ++m)                                  \
    _Pragma("unroll") for (int n = 0; n < 8; ++n)                                  \
        acc[m][n] = mfma16(pa[m], pb[n], acc[m][n]);                               \
    __builtin_amdgcn_s_setprio(0);                                                 \
  } while (0)

  ISSUE(xa, xb, 0, 0);
  ISSUE(ya, yb, 0, 1);
#pragma unroll
  for (int s = 0; s < 32; ++s) {
    const int t2 = (s + 2) >> 1, k2 = (s + 2) & 1;
    if ((s & 1) == 0) {
      MM(xa, xb);
      if (s + 2 < 32) ISSUE(xa, xb, t2, k2);
    } else {
      MM(ya, yb);
      if (s + 2 < 32) ISSUE(ya, yb, t2, k2);
    }
  }
#undef ISSUE
#undef MM

  // epilogue: scatter to Q / K(+64) / V^T(+64)
  const int slot = by >> 3;
  const int csIn = (by & 7) * 128;
  const float sc = (slot == 0) ? 0.18033688011112042f : (alphap[0] * halfp[0]);
#pragma unroll
  for (int m = 0; m < 4; ++m) {
    const int grow0 = bx * 256 + wv * 64 + m * 16 + lg * 4;
#pragma unroll
    for (int n = 0; n < 8; ++n) {
      const int gcol = csIn + n * 16 + lr;
      const int h = gcol >> 6, d = gcol & 63;
#pragma unroll
      for (int j = 0; j < 4; ++j) {
        const int grow = grow0 + j;
        const int b = grow >> 10, nn = grow & 1023;
        const int bh = b * 16 + h;
        const unsigned short u = f2bf(acc[m][n][j] * sc);
        if (slot == 0) {
          Qg[((size_t)bh * NSEQ + nn) * NHD + d] = u;
        } else if (slot == 1) {
          const int kv = NP + nn;
          const int t = kv >> 6, mk = (kv >> 4) & 3, lrk = kv & 15;
          const int kkk = d >> 5, lgk = (d >> 3) & 3, e = d & 7;
          Kf[(size_t)bh * BHSZ + (size_t)((t * 4 + mk) * 2 + kkk) * 512 + (lgk * 16 + lrk) * 8 + e] = u;
        } else {
          const int kv = NP + nn;
          const int t = kv >> 6, kkv = (kv >> 5) & 1, lgv = (kv >> 3) & 3, e = kv & 7;
          const int df = d >> 4, lrv = d & 15;
          Vf[(size_t)bh * BHSZ + (size_t)((t * 4 + df) * 2 + kkv) * 512 + (lgv * 16 + lrv) * 8 + e] = u;
        }
      }
    }
  }
}

// ---------------- proj GEMM (r11-proven: 64x64 wave-tile, 2-deep, no LDS) ----------
__global__ __launch_bounds__(256, 2)
void gemm_proj(const unsigned short* __restrict__ Af, const unsigned short* __restrict__ Bf,
               float* __restrict__ Cout, const float* __restrict__ bias) {
  const int tid = threadIdx.x, lane = tid & 63, wv = tid >> 6;
  const int wr = wv >> 1, wc = wv & 1;
  const int lg = lane >> 4, lr = lane & 15;
  const int bx = blockIdx.x, by = blockIdx.y;

  const unsigned short* Ab = Af + (size_t)bx * 131072 + wr * 4096 + lane * 8;
  const unsigned short* Bb = Bf + (size_t)by * 131072 + wc * 4096 + lane * 8;

  f32x4 acc[4][4] = {};
  bf16x8 aC[2][4], bC[2][4], aN[2][4], bN[2][4];

#define LOADA(dst, t)                                                          \
  _Pragma("unroll") for (int kk = 0; kk < 2; ++kk)                             \
  _Pragma("unroll") for (int m = 0; m < 4; ++m)                                \
      dst[kk][m] = *(const bf16x8*)(Ab + (size_t)(t) * 8192 + kk * 2048 + m * 512)
#define LOADB(dst, t)                                                          \
  _Pragma("unroll") for (int kk = 0; kk < 2; ++kk)                             \
  _Pragma("unroll") for (int n = 0; n < 4; ++n)                                \
      dst[kk][n] = *(const bf16x8*)(Bb + (size_t)(t) * 8192 + kk * 2048 + n * 512)

  LOADA(aC, 0);
  LOADB(bC, 0);
#pragma unroll
  for (int t = 0; t < 16; ++t) {
    if (t < 15) { LOADA(aN, t + 1); LOADB(bN, t + 1); }
    __builtin_amdgcn_s_setprio(1);
#pragma unroll
    for (int kk = 0; kk < 2; ++kk)
#pragma unroll
      for (int m = 0; m < 4; ++m)
#pragma unroll
        for (int n = 0; n < 4; ++n)
          acc[m][n] = mfma16(aC[kk][m], bC[kk][n], acc[m][n]);
    __builtin_amdgcn_s_setprio(0);
#pragma unroll
    for (int kk = 0; kk < 2; ++kk)
#pragma unroll
      for (int i = 0; i < 4; ++i) { aC[kk][i] = aN[kk][i]; bC[kk][i] = bN[kk][i]; }
  }
#undef LOADA
#undef LOADB

#pragma unroll
  for (int m = 0; m < 4; ++m) {
    const int grow0 = bx * 128 + wr * 64 + m * 16 + lg * 4;
#pragma unroll
    for (int n = 0; n < 4; ++n) {
      const int gcol = by * 128 + wc * 64 + n * 16 + lr;
      const float bb = bias[gcol];
#pragma unroll
      for (int j = 0; j < 4; ++j)
        Cout[(size_t)(grow0 + j) * NC + gcol] = acc[m][n][j] + bb;
    }
  }
}

// ---------------- flash attention: barrier-free, cvt_pk P-pack, deferred l-reduce ----
__global__ __launch_bounds__(256, 3)
void attn_fwd(const unsigned short* __restrict__ Qg, const unsigned short* __restrict__ Kf,
              const unsigned short* __restrict__ Vf, unsigned short* __restrict__ Oat) {
  __shared__ __align__(16) unsigned short Plds[4 * 32 * 64];
  const int tid = threadIdx.x, lane = tid & 63, wv = tid >> 6;
  const int bh = blockIdx.x & 127;
  const int q0 = (blockIdx.x >> 7) * 128;
  const int lg = lane >> 4, lr = lane & 15;

  bf16x8 bq[2][2];
#pragma unroll
  for (int nq = 0; nq < 2; ++nq)
#pragma unroll
    for (int kk = 0; kk < 2; ++kk)
      bq[nq][kk] = *(const bf16x8*)(Qg + ((size_t)bh * NSEQ + q0 + wv * 32 + nq * 16 + lr) * NHD + kk * 32 + lg * 8);

  f32x4 oac[2][4] = {};
  float mrun[2] = {-1e30f, -1e30f};
  float lrun[2] = {0.f, 0.f};  // per-lane partial; cross-lane reduced once at end

  const unsigned short* Kb = Kf + (size_t)bh * BHSZ + lane * 8;
  const unsigned short* Vb = Vf + (size_t)bh * BHSZ + lane * 8;
  unsigned short* Pw = Plds + wv * 2048;

  for (int t = 0; t < 17; ++t) {
    bf16x8 ak[4][2];
#pragma unroll
    for (int mk = 0; mk < 4; ++mk)
#pragma unroll
      for (int kk = 0; kk < 2; ++kk)
        ak[mk][kk] = *(const bf16x8*)(Kb + (size_t)((t * 4 + mk) * 2 + kk) * 512);

    f32x4 sa[4][2] = {};
    __builtin_amdgcn_s_setprio(1);
#pragma unroll
    for (int kk = 0; kk < 2; ++kk)
#pragma unroll
      for (int mk = 0; mk < 4; ++mk)
#pragma unroll
        for (int nq = 0; nq < 2; ++nq)
          sa[mk][nq] = mfma16(ak[mk][kk], bq[nq][kk], sa[mk][nq]);
    __builtin_amdgcn_s_setprio(0);

    bf16x8 bv[4][2];
#pragma unroll
    for (int df = 0; df < 4; ++df)
#pragma unroll
      for (int kk = 0; kk < 2; ++kk)
        bv[df][kk] = *(const bf16x8*)(Vb + (size_t)((t * 4 + df) * 2 + kk) * 512);

    float tmx[2];
#pragma unroll
    for (int nq = 0; nq < 2; ++nq) {
      f32x4 m4 = sa[0][nq];
#pragma unroll
      for (int mk = 1; mk < 4; ++mk)
#pragma unroll
        for (int j = 0; j < 4; ++j) m4[j] = fmaxf(m4[j], sa[mk][nq][j]);
      float tm = fmaxf(fmaxf(m4[0], m4[1]), fmaxf(m4[2], m4[3]));
      tm = fmaxf(tm, __shfl_xor(tm, 16));
      tm = fmaxf(tm, __shfl_xor(tm, 32));
      tmx[nq] = tm;
    }
    const bool upd = !__all((tmx[0] <= mrun[0] + 8.f) && (tmx[1] <= mrun[1] + 8.f));
    if (upd) {
      const float nm0 = fmaxf(mrun[0], tmx[0]);
      const float nm1 = fmaxf(mrun[1], tmx[1]);
      const float e0 = __builtin_amdgcn_exp2f(mrun[0] - nm0);
      const float e1 = __builtin_amdgcn_exp2f(mrun[1] - nm1);
      mrun[0] = nm0; mrun[1] = nm1;
      lrun[0] *= e0; lrun[1] *= e1;
#pragma unroll
      for (int m = 0; m < 2; ++m)
#pragma unroll
        for (int j = 0; j < 4; ++j) {
          const float fe = __shfl(m ? e1 : e0, lg * 4 + j, 16);
#pragma unroll
          for (int df = 0; df < 4; ++df) oac[m][df][j] *= fe;
        }
    }
#pragma unroll
    for (int nq = 0; nq < 2; ++nq) {
#pragma unroll
      for (int mk = 0; mk < 4; ++mk)
#pragma unroll
        for (int j = 0; j < 4; ++j)
          sa[mk][nq][j] = __builtin_amdgcn_exp2f(sa[mk][nq][j] - mrun[nq]);
      f32x4 s4 = sa[0][nq];
#pragma unroll
      for (int mk = 1; mk < 4; ++mk)
#pragma unroll
        for (int j = 0; j < 4; ++j) s4[j] += sa[mk][nq][j];
      lrun[nq] += (s4[0] + s4[1]) + (s4[2] + s4[3]);  // per-lane partial (reduced at end)
      const int q = nq * 16 + lr;
#pragma unroll
      for (int mk = 0; mk < 4; ++mk) {
        const int c = mk * 2 + (lg >> 1);
        uint2 uu;
        uu.x = pk2bf(sa[mk][nq][0], sa[mk][nq][1]);  // v_cvt_pk_bf16_f32
        uu.y = pk2bf(sa[mk][nq][2], sa[mk][nq][3]);
        *(uint2*)(Pw + q * 64 + ((c ^ (q & 7)) << 3) + (lg & 1) * 4) = uu;
      }
    }

    __builtin_amdgcn_s_setprio(1);
#pragma unroll
    for (int kk = 0; kk < 2; ++kk) {
      bf16x8 ap[2];
#pragma unroll
      for (int m = 0; m < 2; ++m) {
        const int q = m * 16 + lr;
        const int pos = (kk * 4 + lg) ^ (q & 7);
        ap[m] = *(const bf16x8*)(Pw + q * 64 + pos * 8);
      }
#pragma unroll
      for (int m = 0; m < 2; ++m)
#pragma unroll
        for (int df = 0; df < 4; ++df)
          oac[m][df] = mfma16(ap[m], bv[df][kk], oac[m][df]);
    }
    __builtin_amdgcn_s_setprio(0);
  }

  // deferred cross-lane l reduce (linear; esc scaling was lane-uniform)
#pragma unroll
  for (int nq = 0; nq < 2; ++nq) {
    lrun[nq] += __shfl_xor(lrun[nq], 16);
    lrun[nq] += __shfl_xor(lrun[nq], 32);
  }

  // epilogue: write O fragment-packed (proj-A layout) so gemm_proj streams it
  const int bidx = bh >> 4, h = bh & 15;
  const float l0 = 1.f / lrun[0], l1 = 1.f / lrun[1];
#pragma unroll
  for (int m = 0; m < 2; ++m) {
#pragma unroll
    for (int j = 0; j < 4; ++j) {
      const float fi = __shfl(m ? l1 : l0, lg * 4 + j, 16);
      const int grow = bidx * NSEQ + q0 + wv * 32 + m * 16 + lg * 4 + j;
#pragma unroll
      for (int df = 0; df < 4; ++df) {
        const int col = h * 64 + df * 16 + lr;
        Oat[fa_elem(grow, col)] = f2bf(oac[m][df][j] * fi);
      }
    }
  }
}

// ---------------- launch ----------------
extern "C" void kernel_launch(void* const* d_in, const int* in_sizes, int n_in,
                              void* d_out, int out_size, void* d_ws, size_t ws_size,
                              hipStream_t stream) {
  const float* x      = (const float*)d_in[0];
  const float* prompt = (const float*)d_in[1];
  const float* alpha  = (const float*)d_in[2];
  const float* halfa  = (const float*)d_in[3];
  const float* Wqkv   = (const float*)d_in[4];
  const float* Wproj  = (const float*)d_in[5];
  const float* bproj  = (const float*)d_in[6];
  float* out = (float*)d_out;

  unsigned short* ws    = (unsigned short*)d_ws;
  unsigned short* x_bf  = ws;                                  // frag-packed
  unsigned short* w_bf  = x_bf + (size_t)8192 * 1024;          // frag-packed
  unsigned short* wp_bf = w_bf + (size_t)3072 * 1024;          // frag-packed
  unsigned short* Qg    = wp_bf + (size_t)1024 * 1024;         // row-major
  unsigned short* Kf    = Qg + (size_t)NB * NH * NSEQ * NHD;   // attn-frag-packed
  unsigned short* Vf    = Kf + (size_t)128 * BHSZ;             // attn-frag-packed
  unsigned short* Oat   = Vf + (size_t)128 * BHSZ;             // frag-packed

  pack_fused<<<6656, 256, 0, stream>>>(x, Wqkv, Wproj, prompt, x_bf, w_bf, wp_bf,
                                       Kf, Vf, alpha);

  // QKV: M=8192 N=3072 -> 32 x 24 blocks of 256x128 (64x128 wave-tile)
  gemm_qkv_w<<<dim3(32, 24), 256, 0, stream>>>(x_bf, w_bf, Qg, Kf, Vf, alpha, halfa);
  attn_fwd<<<1024, 256, 0, stream>>>(Qg, Kf, Vf, Oat);
  // proj: M=8192 N=1024 -> 64 x 8 of 128^2 (r11-proven 64x64 wave-tile)
  gemm_proj<<<dim3(64, 8), 256, 0, stream>>>(Oat, wp_bf, out, bproj);
}

// Round 17
// 145.802 us; speedup vs baseline: 1.3093x; 1.0462x over previous
//
#include <hip/hip_runtime.h>

typedef float f32x4 __attribute__((ext_vector_type(4)));
typedef short bf16x8 __attribute__((ext_vector_type(8)));

#define NB 8
#define NH 16
#define NSEQ 1024
#define NP 64
#define NKV 1088
#define NC 1024
#define NHD 64
#define BHSZ 69632  // per-(b,h) K/V fragment-packed size = 1088*64

__device__ __forceinline__ unsigned short f2bf(float f) {
  unsigned int u = __builtin_bit_cast(unsigned int, f);
  u += 0x7fffu + ((u >> 16) & 1u);  // RNE
  return (unsigned short)(u >> 16);
}

// packed pair conversion via v_cvt_pk_bf16_f32 (RNE): lo = a, hi = b
__device__ __forceinline__ unsigned pk2bf(float a, float b) {
  unsigned r;
  asm("v_cvt_pk_bf16_f32 %0, %1, %2" : "=v"(r) : "v"(a), "v"(b));
  return r;
}

__device__ __forceinline__ f32x4 mfma16(bf16x8 a, bf16x8 b, f32x4 c) {
  return __builtin_amdgcn_mfma_f32_16x16x32_bf16(a, b, c, 0, 0, 0);
}

// fragment-packed address (element granularity) for a row-major [R][1024] matrix
// (GEMM A/B operands). row = panel*128 + half*64 + m*16 + lr ; k = t*64 + kk*32 + lg*8 + e
__device__ __forceinline__ size_t fa_elem(int r, int k) {
  return (size_t)(r >> 7) * 131072 + (size_t)(k >> 6) * 8192 + ((r >> 6) & 1) * 4096 +
         ((k >> 5) & 1) * 2048 + ((r >> 4) & 3) * 512 + (((k >> 3) & 3) * 16 + (r & 15)) * 8 +
         (k & 7);
}

// ---------------- fused pack kernel ----------------
__device__ __forceinline__ void fragpack_chunk(const float* __restrict__ src,
                                               unsigned short* __restrict__ dst, int c) {
  const int lane = c & 63, m = (c >> 6) & 3, kk = (c >> 8) & 1, wr = (c >> 9) & 1,
            t = (c >> 10) & 15, panel = c >> 14;
  const int row = panel * 128 + wr * 64 + m * 16 + (lane & 15);
  const int k = t * 64 + kk * 32 + (lane >> 4) * 8;
  const float* s = src + (size_t)row * 1024 + k;
  const float4 v0 = *(const float4*)s;
  const float4 v1 = *(const float4*)(s + 4);
  ushort4 o0, o1;
  o0.x = f2bf(v0.x); o0.y = f2bf(v0.y); o0.z = f2bf(v0.z); o0.w = f2bf(v0.w);
  o1.x = f2bf(v1.x); o1.y = f2bf(v1.y); o1.z = f2bf(v1.z); o1.w = f2bf(v1.w);
  *(ushort4*)(dst + (size_t)c * 8) = o0;
  *(ushort4*)(dst + (size_t)c * 8 + 4) = o1;
}

__global__ void pack_fused(const float* __restrict__ x, const float* __restrict__ wq,
                           const float* __restrict__ wp, const float* __restrict__ prompt,
                           unsigned short* __restrict__ xd, unsigned short* __restrict__ wqd,
                           unsigned short* __restrict__ wpd, unsigned short* __restrict__ Kf,
                           unsigned short* __restrict__ Vf, const float* __restrict__ alpha) {
  int gid = blockIdx.x * 256 + threadIdx.x;
  if (gid < 1048576) {                       // x: 8192x1024
    fragpack_chunk(x, xd, gid);
  } else if (gid < 1441792) {                // Wqkv: 3072x1024
    fragpack_chunk(wq, wqd, gid - 1048576);
  } else if (gid < 1572864) {                // Wproj: 1024x1024
    fragpack_chunk(wp, wpd, gid - 1441792);
  } else {                                   // prompt prefix (t=0 tiles of K/V frag layout)
    int i = gid - 1572864;                   // 131072
    float a = alpha[0];
    int d4 = i & 15, p = (i >> 4) & 63, h = (i >> 10) & 15, b = i >> 14;
    const int bh = b * 16 + h;
    const int d0 = d4 * 4;
    const float4 kv4 = *(const float4*)(prompt + ((((size_t)(b * 2 + 0) * NP + p) * NH + h) * NHD + d0));
    {
      const int mk = p >> 4, lrk = p & 15, kk = d0 >> 5, lg = (d0 >> 3) & 3, e0 = d0 & 7;
      unsigned short* kd = Kf + (size_t)bh * BHSZ + ((mk * 2 + kk) * 4 + lg) * 128 + lrk * 8 + e0;
      kd[0] = f2bf(kv4.x * a); kd[1] = f2bf(kv4.y * a);
      kd[2] = f2bf(kv4.z * a); kd[3] = f2bf(kv4.w * a);
    }
    const float4 vv4 = *(const float4*)(prompt + ((((size_t)(b * 2 + 1) * NP + p) * NH + h) * NHD + d0));
    {
      const int df = d0 >> 4, kk = p >> 5, lg = (p >> 3) & 3, e = p & 7;
      unsigned short* vd = Vf + (size_t)bh * BHSZ + ((df * 2 + kk) * 4 + lg) * 128 + e;
      vd[((d0 + 0) & 15) * 8] = f2bf(vv4.x * a);
      vd[((d0 + 1) & 15) * 8] = f2bf(vv4.y * a);
      vd[((d0 + 2) & 15) * 8] = f2bf(vv4.z * a);
      vd[((d0 + 3) & 15) * 8] = f2bf(vv4.w * a);
    }
  }
}

// ---------------- QKV GEMM: 64x128 wave-tile direct streaming ------
__global__ __launch_bounds__(256, 2)
void gemm_qkv_w(const unsigned short* __restrict__ Af, const unsigned short* __restrict__ Bf,
                unsigned short* __restrict__ Qg, unsigned short* __restrict__ Kf,
                unsigned short* __restrict__ Vf,
                const float* __restrict__ alphap, const float* __restrict__ halfp) {
  const int tid = threadIdx.x, lane = tid & 63, wv = tid >> 6;
  const int lg = lane >> 4, lr = lane & 15;
  const int bx = blockIdx.x, by = blockIdx.y;  // 32 x 24

  const unsigned short* Abase = Af + (size_t)(bx * 2 + (wv >> 1)) * 131072 + (wv & 1) * 4096 + lane * 8;
  const unsigned short* Bbase = Bf + (size_t)by * 131072 + lane * 8;

  f32x4 acc[4][8] = {};
  bf16x8 xa[4], xb[8], ya[4], yb[8];

#define ISSUE(pa, pb, t, kk)                                                       \
  do {                                                                             \
    _Pragma("unroll") for (int m = 0; m < 4; ++m)                                  \
        pa[m] = *(const bf16x8*)(Abase + (size_t)(t) * 8192 + (kk) * 2048 + m * 512); \
    _Pragma("unroll") for (int n = 0; n < 8; ++n)                                  \
        pb[n] = *(const bf16x8*)(Bbase + (size_t)(t) * 8192 + (kk) * 2048 +        \
                                 (n >> 2) * 4096 + (n & 3) * 512);                 \
  } while (0)

#define MM(pa, pb)                                                                 \
  do {                                                                             \
    __builtin_amdgcn_s_setprio(1);                                                 \
    _Pragma("unroll") for (int m = 0; m < 4; ++m)                                  \
    _Pragma("unroll") for (int n = 0; n < 8; ++n)                                  \
        acc[m][n] = mfma16(pa[m], pb[n], acc[m][n]);                               \
    __builtin_amdgcn_s_setprio(0);                                                 \
  } while (0)

  ISSUE(xa, xb, 0, 0);
  ISSUE(ya, yb, 0, 1);
#pragma unroll
  for (int s = 0; s < 32; ++s) {
    const int t2 = (s + 2) >> 1, k2 = (s + 2) & 1;
    if ((s & 1) == 0) {
      MM(xa, xb);
      if (s + 2 < 32) ISSUE(xa, xb, t2, k2);
    } else {
      MM(ya, yb);
      if (s + 2 < 32) ISSUE(ya, yb, t2, k2);
    }
  }
#undef ISSUE
#undef MM

  // epilogue: scatter to Q / K(+64) / V^T(+64)
  const int slot = by >> 3;
  const int csIn = (by & 7) * 128;
  const float sc = (slot == 0) ? 0.18033688011112042f : (alphap[0] * halfp[0]);
#pragma unroll
  for (int m = 0; m < 4; ++m) {
    const int grow0 = bx * 256 + wv * 64 + m * 16 + lg * 4;
    const int b = grow0 >> 10, nn0 = grow0 & 1023;  // constant over j (grow0 % 4 == 0)
#pragma unroll
    for (int n = 0; n < 8; ++n) {
      const int gcol = csIn + n * 16 + lr;
      const int h = gcol >> 6, d = gcol & 63;
      const int bh = b * 16 + h;
      if (slot == 2) {
        // V^T: 4 j-values land in 4 consecutive e slots of one frag -> one 8B store
        const int kv0 = NP + nn0;
        const int t = kv0 >> 6, kkv = (kv0 >> 5) & 1, lgv = (kv0 >> 3) & 3, e0 = kv0 & 7;
        const int df = d >> 4, lrv = d & 15;
        uint2 uu;
        uu.x = pk2bf(acc[m][n][0] * sc, acc[m][n][1] * sc);
        uu.y = pk2bf(acc[m][n][2] * sc, acc[m][n][3] * sc);
        *(uint2*)(Vf + (size_t)bh * BHSZ + (size_t)((t * 4 + df) * 2 + kkv) * 512 +
                  (lgv * 16 + lrv) * 8 + e0) = uu;
      } else {
#pragma unroll
        for (int j = 0; j < 4; ++j) {
          const int nn = nn0 + j;
          const unsigned short u = f2bf(acc[m][n][j] * sc);
          if (slot == 0) {
            Qg[((size_t)bh * NSEQ + nn) * NHD + d] = u;
          } else {
            const int kv = NP + nn;
            const int t = kv >> 6, mk = (kv >> 4) & 3, lrk = kv & 15;
            const int kkk = d >> 5, lgk = (d >> 3) & 3, e = d & 7;
            Kf[(size_t)bh * BHSZ + (size_t)((t * 4 + mk) * 2 + kkk) * 512 + (lgk * 16 + lrk) * 8 + e] = u;
          }
        }
      }
    }
  }
}

// ---------------- proj GEMM (r11-proven: 64x64 wave-tile, 2-deep, no LDS) ----------
__global__ __launch_bounds__(256, 2)
void gemm_proj(const unsigned short* __restrict__ Af, const unsigned short* __restrict__ Bf,
               float* __restrict__ Cout, const float* __restrict__ bias) {
  const int tid = threadIdx.x, lane = tid & 63, wv = tid >> 6;
  const int wr = wv >> 1, wc = wv & 1;
  const int lg = lane >> 4, lr = lane & 15;
  const int bx = blockIdx.x, by = blockIdx.y;

  const unsigned short* Ab = Af + (size_t)bx * 131072 + wr * 4096 + lane * 8;
  const unsigned short* Bb = Bf + (size_t)by * 131072 + wc * 4096 + lane * 8;

  f32x4 acc[4][4] = {};
  bf16x8 aC[2][4], bC[2][4], aN[2][4], bN[2][4];

#define LOADA(dst, t)                                                          \
  _Pragma("unroll") for (int kk = 0; kk < 2; ++kk)                             \
  _Pragma("unroll") for (int m = 0; m < 4; ++m)                                \
      dst[kk][m] = *(const bf16x8*)(Ab + (size_t)(t) * 8192 + kk * 2048 + m * 512)
#define LOADB(dst, t)                                                          \
  _Pragma("unroll") for (int kk = 0; kk < 2; ++kk)                             \
  _Pragma("unroll") for (int n = 0; n < 4; ++n)                                \
      dst[kk][n] = *(const bf16x8*)(Bb + (size_t)(t) * 8192 + kk * 2048 + n * 512)

  LOADA(aC, 0);
  LOADB(bC, 0);
#pragma unroll
  for (int t = 0; t < 16; ++t) {
    if (t < 15) { LOADA(aN, t + 1); LOADB(bN, t + 1); }
    __builtin_amdgcn_s_setprio(1);
#pragma unroll
    for (int kk = 0; kk < 2; ++kk)
#pragma unroll
      for (int m = 0; m < 4; ++m)
#pragma unroll
        for (int n = 0; n < 4; ++n)
          acc[m][n] = mfma16(aC[kk][m], bC[kk][n], acc[m][n]);
    __builtin_amdgcn_s_setprio(0);
#pragma unroll
    for (int kk = 0; kk < 2; ++kk)
#pragma unroll
      for (int i = 0; i < 4; ++i) { aC[kk][i] = aN[kk][i]; bC[kk][i] = bN[kk][i]; }
  }
#undef LOADA
#undef LOADB

#pragma unroll
  for (int m = 0; m < 4; ++m) {
    const int grow0 = bx * 128 + wr * 64 + m * 16 + lg * 4;
#pragma unroll
    for (int n = 0; n < 4; ++n) {
      const int gcol = by * 128 + wc * 64 + n * 16 + lr;
      const float bb = bias[gcol];
#pragma unroll
      for (int j = 0; j < 4; ++j)
        Cout[(size_t)(grow0 + j) * NC + gcol] = acc[m][n][j] + bb;
    }
  }
}

// ---------------- flash attention: barrier-free, l-via-MFMA (ones trick) ----
__global__ __launch_bounds__(256, 3)
void attn_fwd(const unsigned short* __restrict__ Qg, const unsigned short* __restrict__ Kf,
              const unsigned short* __restrict__ Vf, unsigned short* __restrict__ Oat) {
  __shared__ __align__(16) unsigned short Plds[4 * 32 * 64];
  const int tid = threadIdx.x, lane = tid & 63, wv = tid >> 6;
  const int bh = blockIdx.x & 127;
  const int q0 = (blockIdx.x >> 7) * 128;
  const int lg = lane >> 4, lr = lane & 15;

  bf16x8 bq[2][2];
#pragma unroll
  for (int nq = 0; nq < 2; ++nq)
#pragma unroll
    for (int kk = 0; kk < 2; ++kk)
      bq[nq][kk] = *(const bf16x8*)(Qg + ((size_t)bh * NSEQ + q0 + wv * 32 + nq * 16 + lr) * NHD + kk * 32 + lg * 8);

  // ones vector for l-row-sum MFMA (bf16 1.0 = 0x3F80)
  const bf16x8 bones = {(short)0x3F80, (short)0x3F80, (short)0x3F80, (short)0x3F80,
                        (short)0x3F80, (short)0x3F80, (short)0x3F80, (short)0x3F80};

  f32x4 oac[2][4] = {};
  f32x4 lac[2] = {};           // l accumulator: lac[m][j] = l[q = m*16+lg*4+j] (in-lane)
  float mrun[2] = {-1e30f, -1e30f};

  const unsigned short* Kb = Kf + (size_t)bh * BHSZ + lane * 8;
  const unsigned short* Vb = Vf + (size_t)bh * BHSZ + lane * 8;
  unsigned short* Pw = Plds + wv * 2048;

  for (int t = 0; t < 17; ++t) {
    bf16x8 ak[4][2];
#pragma unroll
    for (int mk = 0; mk < 4; ++mk)
#pragma unroll
      for (int kk = 0; kk < 2; ++kk)
        ak[mk][kk] = *(const bf16x8*)(Kb + (size_t)((t * 4 + mk) * 2 + kk) * 512);

    f32x4 sa[4][2] = {};
    __builtin_amdgcn_s_setprio(1);
#pragma unroll
    for (int kk = 0; kk < 2; ++kk)
#pragma unroll
      for (int mk = 0; mk < 4; ++mk)
#pragma unroll
        for (int nq = 0; nq < 2; ++nq)
          sa[mk][nq] = mfma16(ak[mk][kk], bq[nq][kk], sa[mk][nq]);
    __builtin_amdgcn_s_setprio(0);

    bf16x8 bv[4][2];
#pragma unroll
    for (int df = 0; df < 4; ++df)
#pragma unroll
      for (int kk = 0; kk < 2; ++kk)
        bv[df][kk] = *(const bf16x8*)(Vb + (size_t)((t * 4 + df) * 2 + kk) * 512);

    float tmx[2];
#pragma unroll
    for (int nq = 0; nq < 2; ++nq) {
      f32x4 m4 = sa[0][nq];
#pragma unroll
      for (int mk = 1; mk < 4; ++mk)
#pragma unroll
        for (int j = 0; j < 4; ++j) m4[j] = fmaxf(m4[j], sa[mk][nq][j]);
      float tm = fmaxf(fmaxf(m4[0], m4[1]), fmaxf(m4[2], m4[3]));
      tm = fmaxf(tm, __shfl_xor(tm, 16));
      tm = fmaxf(tm, __shfl_xor(tm, 32));
      tmx[nq] = tm;
    }
    const bool upd = !__all((tmx[0] <= mrun[0] + 8.f) && (tmx[1] <= mrun[1] + 8.f));
    if (upd) {
      const float nm0 = fmaxf(mrun[0], tmx[0]);
      const float nm1 = fmaxf(mrun[1], tmx[1]);
      const float e0 = __builtin_amdgcn_exp2f(mrun[0] - nm0);
      const float e1 = __builtin_amdgcn_exp2f(mrun[1] - nm1);
      mrun[0] = nm0; mrun[1] = nm1;
#pragma unroll
      for (int m = 0; m < 2; ++m)
#pragma unroll
        for (int j = 0; j < 4; ++j) {
          const float fe = __shfl(m ? e1 : e0, lg * 4 + j, 16);
          lac[m][j] *= fe;
#pragma unroll
          for (int df = 0; df < 4; ++df) oac[m][df][j] *= fe;
        }
    }
    // P = 2^(S - m); pack bf16 and store to per-wave LDS (l comes from MFMA below)
#pragma unroll
    for (int nq = 0; nq < 2; ++nq) {
#pragma unroll
      for (int mk = 0; mk < 4; ++mk)
#pragma unroll
        for (int j = 0; j < 4; ++j)
          sa[mk][nq][j] = __builtin_amdgcn_exp2f(sa[mk][nq][j] - mrun[nq]);
      const int q = nq * 16 + lr;
#pragma unroll
      for (int mk = 0; mk < 4; ++mk) {
        const int c = mk * 2 + (lg >> 1);
        uint2 uu;
        uu.x = pk2bf(sa[mk][nq][0], sa[mk][nq][1]);
        uu.y = pk2bf(sa[mk][nq][2], sa[mk][nq][3]);
        *(uint2*)(Pw + q * 64 + ((c ^ (q & 7)) << 3) + (lg & 1) * 4) = uu;
      }
    }

    __builtin_amdgcn_s_setprio(1);
#pragma unroll
    for (int kk = 0; kk < 2; ++kk) {
      bf16x8 ap[2];
#pragma unroll
      for (int m = 0; m < 2; ++m) {
        const int q = m * 16 + lr;
        const int pos = (kk * 4 + lg) ^ (q & 7);
        ap[m] = *(const bf16x8*)(Pw + q * 64 + pos * 8);
      }
#pragma unroll
      for (int m = 0; m < 2; ++m) {
#pragma unroll
        for (int df = 0; df < 4; ++df)
          oac[m][df] = mfma16(ap[m], bv[df][kk], oac[m][df]);
        lac[m] = mfma16(ap[m], bones, lac[m]);  // row-sums of P (same bf16 P as numerator)
      }
    }
    __builtin_amdgcn_s_setprio(0);
  }

  // epilogue: write O fragment-packed (proj-A layout); fi = 1/l is in-lane via lac
  const int bidx = bh >> 4, h = bh & 15;
#pragma unroll
  for (int m = 0; m < 2; ++m) {
#pragma unroll
    for (int j = 0; j < 4; ++j) {
      const float fi = 1.f / lac[m][j];
      const int grow = bidx * NSEQ + q0 + wv * 32 + m * 16 + lg * 4 + j;
#pragma unroll
      for (int df = 0; df < 4; ++df) {
        const int col = h * 64 + df * 16 + lr;
        Oat[fa_elem(grow, col)] = f2bf(oac[m][df][j] * fi);
      }
    }
  }
}

// ---------------- launch ----------------
extern "C" void kernel_launch(void* const* d_in, const int* in_sizes, int n_in,
                              void* d_out, int out_size, void* d_ws, size_t ws_size,
                              hipStream_t stream) {
  const float* x      = (const float*)d_in[0];
  const float* prompt = (const float*)d_in[1];
  const float* alpha  = (const float*)d_in[2];
  const float* halfa  = (const float*)d_in[3];
  const float* Wqkv   = (const float*)d_in[4];
  const float* Wproj  = (const float*)d_in[5];
  const float* bproj  = (const float*)d_in[6];
  float* out = (float*)d_out;

  unsigned short* ws    = (unsigned short*)d_ws;
  unsigned short* x_bf  = ws;                                  // frag-packed
  unsigned short* w_bf  = x_bf + (size_t)8192 * 1024;          // frag-packed
  unsigned short* wp_bf = w_bf + (size_t)3072 * 1024;          // frag-packed
  unsigned short* Qg    = wp_bf + (size_t)1024 * 1024;         // row-major
  unsigned short* Kf    = Qg + (size_t)NB * NH * NSEQ * NHD;   // attn-frag-packed
  unsigned short* Vf    = Kf + (size_t)128 * BHSZ;             // attn-frag-packed
  unsigned short* Oat   = Vf + (size_t)128 * BHSZ;             // frag-packed

  pack_fused<<<6656, 256, 0, stream>>>(x, Wqkv, Wproj, prompt, x_bf, w_bf, wp_bf,
                                       Kf, Vf, alpha);

  // QKV: M=8192 N=3072 -> 32 x 24 blocks of 256x128 (64x128 wave-tile)
  gemm_qkv_w<<<dim3(32, 24), 256, 0, stream>>>(x_bf, w_bf, Qg, Kf, Vf, alpha, halfa);
  attn_fwd<<<1024, 256, 0, stream>>>(Qg, Kf, Vf, Oat);
  // proj: M=8192 N=1024 -> 64 x 8 of 128^2 (r11-proven 64x64 wave-tile)
  gemm_proj<<<dim3(64, 8), 256, 0, stream>>>(Oat, wp_bf, out, bproj);
}